// Round 18
// baseline (174.641 us; speedup 1.0000x reference)
//
#include <hip/hip_runtime.h>

#define NN 384
#define RR 8
#define NR (NN * RR)   // 3072
#define IPAD 385       // padded i-stride for A2c (breaks c-dimension bank aliasing)
#define GSTR 72        // Gh row stride in f16 (144B rows -> bank spread)

typedef _Float16 half4v __attribute__((ext_vector_type(4)));
typedef _Float16 half8v __attribute__((ext_vector_type(8)));
typedef float f32x4 __attribute__((ext_vector_type(4)));

// out[b,i] = sum_{a,b2,c} A[a,i,b2]*Bf[b2,j_b,c]*C[c,k_b,a]
// G[b2,a] = sum_c Bf[b2,j,c]*C[c,k,a];  out[b,i] = sum_p A2[i,p]*G[p], p=a*8+b2.
// r18 = r17 (wave-autonomous, proven) with 256 pairs/block: each wave runs TWO
// sequential 16-pair sets, reusing its private Gh region (same-wave DS ordering
// makes this race-free). Halves the number of A2-staging prefixes (4096->2048).
__global__ __launch_bounds__(512, 4)
void dtn_mfma16w2(const float* __restrict__ A, const float* __restrict__ Bf,
                  const float* __restrict__ C, const int* __restrict__ x,
                  float* __restrict__ out)
{
    __shared__ __align__(16) _Float16 A2c[8 * IPAD * 8];   // 49280 B
    __shared__ __align__(16) _Float16 Gh[8 * 16 * GSTR];   // 18432 B (wave-private 2304B each)

    const int t = threadIdx.x;
    const long b0 = (long)blockIdx.x * 256;   // 256 pairs per block (8 waves x 16 x 2 sets)

    // ---- Stage A2c[(a*IPAD+i)*8+e] = f16(A[a*NR + i*8 + e]); 3072 chunks, 6 iters.
    #pragma unroll
    for (int it = 0; it < 6; ++it) {
        const int idx = t + it * 512;     // 0..3071
        const int i = idx >> 3;
        const int a = idx & 7;
        const float4* src = reinterpret_cast<const float4*>(A + (size_t)a * NR + (size_t)i * RR);
        const float4 f0 = src[0];
        const float4 f1 = src[1];
        half8v h;
        h[0] = (_Float16)f0.x; h[1] = (_Float16)f0.y; h[2] = (_Float16)f0.z; h[3] = (_Float16)f0.w;
        h[4] = (_Float16)f1.x; h[5] = (_Float16)f1.y; h[6] = (_Float16)f1.z; h[7] = (_Float16)f1.w;
        *reinterpret_cast<half8v*>(&A2c[(size_t)(a * IPAD + i) * 8]) = h;
    }
    __syncthreads();   // the ONLY block-wide barrier

    const int lane = t & 63;
    const int w    = t >> 6;                       // wave 0..7
    _Float16* Ghw  = &Gh[w * 16 * GSTR];           // wave-private G region
    const int a16  = lane & 15;
    const int q    = lane >> 4;                    // 0..3

    #pragma unroll 1
    for (int s = 0; s < 2; ++s) {
        const long p0 = b0 + s * 128 + w * 16;     // this wave's 16 pairs for set s

        // ---- G phase (r4-proven per-lane map): lane -> pair bl = lane>>2, a0 = (lane&3)*2.
        {
            const int bl = lane >> 2;
            const int a0 = (lane & 3) * 2;
            const long pair = p0 + bl;
            const int j = x[2 * pair];
            const int k = x[2 * pair + 1];
            const float* Bj = Bf + (size_t)j * RR;       // Bf[b2,j,c] at Bj[b2*NR + c]
            const float* Ck = C + (size_t)k * RR + a0;   // C[c,k,a0+d] at Ck[c*NR + d]
            float2 ck[8];
            #pragma unroll
            for (int c = 0; c < 8; ++c)
                ck[c] = *reinterpret_cast<const float2*>(Ck + (size_t)c * NR);
            half8v h0, h1;
            #pragma unroll
            for (int b2 = 0; b2 < 8; ++b2) {
                const float4* br = reinterpret_cast<const float4*>(Bj + (size_t)b2 * NR);
                const float4 r0 = br[0];
                const float4 r1 = br[1];
                const float s0 = r0.x * ck[0].x + r0.y * ck[1].x + r0.z * ck[2].x + r0.w * ck[3].x
                               + r1.x * ck[4].x + r1.y * ck[5].x + r1.z * ck[6].x + r1.w * ck[7].x;
                const float s1 = r0.x * ck[0].y + r0.y * ck[1].y + r0.z * ck[2].y + r0.w * ck[3].y
                               + r1.x * ck[4].y + r1.y * ck[5].y + r1.z * ck[6].y + r1.w * ck[7].y;
                h0[b2] = (_Float16)s0;
                h1[b2] = (_Float16)s1;
            }
            *reinterpret_cast<half8v*>(&Ghw[bl * GSTR + a0 * 8]) = h0;       // p = a0*8 + b2
            *reinterpret_cast<half8v*>(&Ghw[bl * GSTR + a0 * 8 + 8]) = h1;   // p = (a0+1)*8 + b2
        }
        // Wave-private RAW on LDS: compiler emits lgkmcnt wait; no barrier needed.
        // Set-2 writes cannot race set-1 reads: same-wave DS ops retire in order.

        // ---- A-fragments (r13 map): G-row = a16 (pair), k-windows 0/16/32/48 (+4q).
        const half4v af0 = *reinterpret_cast<const half4v*>(&Ghw[a16 * GSTR +  0 + 4 * q]);
        const half4v af1 = *reinterpret_cast<const half4v*>(&Ghw[a16 * GSTR + 16 + 4 * q]);
        const half4v af2 = *reinterpret_cast<const half4v*>(&Ghw[a16 * GSTR + 32 + 4 * q]);
        const half4v af3 = *reinterpret_cast<const half4v*>(&Ghw[a16 * GSTR + 48 + 4 * q]);

        const long prow0 = p0 + 4 * q;             // D row base (pair) for this lane

        // ---- 24 N-tiles of 16 i; B-frag (r13 map): A2[col=n0+a16][k=16kt+4q+e],
        //      p = 16kt+4q+e -> chunk c = 2kt+(q>>1), elem = 4*(q&1)+e.
        #pragma unroll 2
        for (int nt = 0; nt < 24; ++nt) {
            const int col = nt * 16 + a16;
            f32x4 acc = {0.f, 0.f, 0.f, 0.f};
            const half4v bf0 = *reinterpret_cast<const half4v*>(
                &A2c[(size_t)((0 + (q >> 1)) * IPAD + col) * 8 + 4 * (q & 1)]);
            acc = __builtin_amdgcn_mfma_f32_16x16x16f16(af0, bf0, acc, 0, 0, 0);
            const half4v bf1 = *reinterpret_cast<const half4v*>(
                &A2c[(size_t)((2 + (q >> 1)) * IPAD + col) * 8 + 4 * (q & 1)]);
            acc = __builtin_amdgcn_mfma_f32_16x16x16f16(af1, bf1, acc, 0, 0, 0);
            const half4v bf2 = *reinterpret_cast<const half4v*>(
                &A2c[(size_t)((4 + (q >> 1)) * IPAD + col) * 8 + 4 * (q & 1)]);
            acc = __builtin_amdgcn_mfma_f32_16x16x16f16(af2, bf2, acc, 0, 0, 0);
            const half4v bf3 = *reinterpret_cast<const half4v*>(
                &A2c[(size_t)((6 + (q >> 1)) * IPAD + col) * 8 + 4 * (q & 1)]);
            acc = __builtin_amdgcn_mfma_f32_16x16x16f16(af3, bf3, acc, 0, 0, 0);

            float* op = out + (size_t)prow0 * NN + col;
            op[0]            = acc[0];
            op[(size_t)NN]   = acc[1];
            op[(size_t)2*NN] = acc[2];
            op[(size_t)3*NN] = acc[3];
        }
    }
}

extern "C" void kernel_launch(void* const* d_in, const int* in_sizes, int n_in,
                              void* d_out, int out_size, void* d_ws, size_t ws_size,
                              hipStream_t stream) {
    const float* A  = (const float*)d_in[0];
    const float* Bf = (const float*)d_in[1];
    const float* C  = (const float*)d_in[2];
    const int*   x  = (const int*)d_in[3];
    float* out = (float*)d_out;
    const int B = in_sizes[3] / 2;           // 524288
    dtn_mfma16w2<<<B / 256, 512, 0, stream>>>(A, Bf, C, x, out);
}

// Round 19
// 168.806 us; speedup vs baseline: 1.0346x; 1.0346x over previous
//
#include <hip/hip_runtime.h>

#define NN 384
#define RR 8
#define NR (NN * RR)   // 3072
#define GSTR 72        // Gh row stride in f16 (144B rows -> bank spread)

typedef _Float16 half4v __attribute__((ext_vector_type(4)));
typedef _Float16 half8v __attribute__((ext_vector_type(8)));
typedef float f32x4 __attribute__((ext_vector_type(4)));

// ---------- prep: A (f32) -> A2h (f16) in ws; chunk q == A[8q..8q+8) ----------
// (passed verification in r11/r12 rounds)
__global__ void prep_a2(const float* __restrict__ A, _Float16* __restrict__ A2h) {
    const int q = blockIdx.x * 256 + threadIdx.x;     // 0..3071
    if (q < NN * RR) {
        const float4 f0 = reinterpret_cast<const float4*>(A)[2 * q];
        const float4 f1 = reinterpret_cast<const float4*>(A)[2 * q + 1];
        half8v h;
        h[0] = (_Float16)f0.x; h[1] = (_Float16)f0.y; h[2] = (_Float16)f0.z; h[3] = (_Float16)f0.w;
        h[4] = (_Float16)f1.x; h[5] = (_Float16)f1.y; h[6] = (_Float16)f1.z; h[7] = (_Float16)f1.w;
        reinterpret_cast<half8v*>(A2h)[q] = h;
    }
}

// out[b,i] = sum_{a,b2,c} A[a,i,b2]*Bf[b2,j_b,c]*C[c,k_b,a]
// G[b2,a] = sum_c Bf[b2,j,c]*C[c,k,a];  out[b,i] = sum_p A2[i,p]*G[p], p=a*8+b2.
// r19 = r17 (wave-autonomous, proven) with staging via global_load_lds from
// pre-converted A2h: identity 48KB copy, no cvt, no VGPR round-trip, no pad
// (pad was not changing the bf-read conflict pattern: starts = 4*a16+2(q&1) mod 32).
__global__ __launch_bounds__(512, 4)
void dtn_mfma16g(const _Float16* __restrict__ A2h, const float* __restrict__ Bf,
                 const float* __restrict__ C, const int* __restrict__ x,
                 float* __restrict__ out)
{
    __shared__ __align__(16) _Float16 A2c[8 * NN * 8];     // 49152 B (linear, chunk-major)
    __shared__ __align__(16) _Float16 Gh[8 * 16 * GSTR];   // 18432 B (wave-private 2304B each)

    const int t = threadIdx.x;
    const long b0 = (long)blockIdx.x * 128;   // 128 pairs per block (8 waves x 16)

    // ---- Stage: identity copy A2h -> A2c, 3072 x 16B via global_load_lds.
    // Per-lane dst = A2c + idx*16B with idx = it*512 + t: linear in lane order.
    #pragma unroll
    for (int it = 0; it < 6; ++it) {
        const int idx = it * 512 + t;         // 0..3071
        __builtin_amdgcn_global_load_lds(
            (const __attribute__((address_space(1))) void*)(A2h + (size_t)idx * 8),
            (__attribute__((address_space(3))) void*)(&A2c[(size_t)idx * 8]),
            16, 0, 0);
    }
    __syncthreads();   // the ONLY block-wide barrier (drains vmcnt incl. load_lds)

    const int lane = t & 63;
    const int w    = t >> 6;                       // wave 0..7 owns pairs b0+w*16..+15
    _Float16* Ghw  = &Gh[w * 16 * GSTR];           // wave-private G region

    // ---- G phase (r4-proven per-lane map): lane -> pair bl = lane>>2, a0 = (lane&3)*2.
    {
        const int bl = lane >> 2;
        const int a0 = (lane & 3) * 2;
        const long pair = b0 + w * 16 + bl;
        const int j = x[2 * pair];
        const int k = x[2 * pair + 1];
        const float* Bj = Bf + (size_t)j * RR;       // Bf[b2,j,c] at Bj[b2*NR + c]
        const float* Ck = C + (size_t)k * RR + a0;   // C[c,k,a0+d] at Ck[c*NR + d]
        float2 ck[8];
        #pragma unroll
        for (int c = 0; c < 8; ++c)
            ck[c] = *reinterpret_cast<const float2*>(Ck + (size_t)c * NR);
        half8v h0, h1;
        #pragma unroll
        for (int b2 = 0; b2 < 8; ++b2) {
            const float4* br = reinterpret_cast<const float4*>(Bj + (size_t)b2 * NR);
            const float4 r0 = br[0];
            const float4 r1 = br[1];
            const float s0 = r0.x * ck[0].x + r0.y * ck[1].x + r0.z * ck[2].x + r0.w * ck[3].x
                           + r1.x * ck[4].x + r1.y * ck[5].x + r1.z * ck[6].x + r1.w * ck[7].x;
            const float s1 = r0.x * ck[0].y + r0.y * ck[1].y + r0.z * ck[2].y + r0.w * ck[3].y
                           + r1.x * ck[4].y + r1.y * ck[5].y + r1.z * ck[6].y + r1.w * ck[7].y;
            h0[b2] = (_Float16)s0;
            h1[b2] = (_Float16)s1;
        }
        *reinterpret_cast<half8v*>(&Ghw[bl * GSTR + a0 * 8]) = h0;       // p = a0*8 + b2
        *reinterpret_cast<half8v*>(&Ghw[bl * GSTR + a0 * 8 + 8]) = h1;   // p = (a0+1)*8 + b2
    }
    // Wave-private RAW on LDS: compiler emits lgkmcnt wait; no barrier needed.

    const int a16 = lane & 15;
    const int q   = lane >> 4;   // 0..3

    // ---- A-fragments (r13 map): G-row = a16 (pair), k-windows 0/16/32/48 (+4q).
    const half4v af0 = *reinterpret_cast<const half4v*>(&Ghw[a16 * GSTR +  0 + 4 * q]);
    const half4v af1 = *reinterpret_cast<const half4v*>(&Ghw[a16 * GSTR + 16 + 4 * q]);
    const half4v af2 = *reinterpret_cast<const half4v*>(&Ghw[a16 * GSTR + 32 + 4 * q]);
    const half4v af3 = *reinterpret_cast<const half4v*>(&Ghw[a16 * GSTR + 48 + 4 * q]);

    const long prow0 = b0 + w * 16 + 4 * q;    // D row base (pair) for this lane

    // ---- 24 N-tiles of 16 i; B-frag (r13 map): A2c[chunk = (2kt+(q>>1))*NN + col],
    //      elem offset 4*(q&1);  p = 16kt+4q+e.
    #pragma unroll 2
    for (int nt = 0; nt < 24; ++nt) {
        const int col = nt * 16 + a16;
        f32x4 acc = {0.f, 0.f, 0.f, 0.f};
        const half4v bf0 = *reinterpret_cast<const half4v*>(
            &A2c[(size_t)((0 + (q >> 1)) * NN + col) * 8 + 4 * (q & 1)]);
        acc = __builtin_amdgcn_mfma_f32_16x16x16f16(af0, bf0, acc, 0, 0, 0);
        const half4v bf1 = *reinterpret_cast<const half4v*>(
            &A2c[(size_t)((2 + (q >> 1)) * NN + col) * 8 + 4 * (q & 1)]);
        acc = __builtin_amdgcn_mfma_f32_16x16x16f16(af1, bf1, acc, 0, 0, 0);
        const half4v bf2 = *reinterpret_cast<const half4v*>(
            &A2c[(size_t)((4 + (q >> 1)) * NN + col) * 8 + 4 * (q & 1)]);
        acc = __builtin_amdgcn_mfma_f32_16x16x16f16(af2, bf2, acc, 0, 0, 0);
        const half4v bf3 = *reinterpret_cast<const half4v*>(
            &A2c[(size_t)((6 + (q >> 1)) * NN + col) * 8 + 4 * (q & 1)]);
        acc = __builtin_amdgcn_mfma_f32_16x16x16f16(af3, bf3, acc, 0, 0, 0);

        float* op = out + (size_t)prow0 * NN + col;
        op[0]            = acc[0];
        op[(size_t)NN]   = acc[1];
        op[(size_t)2*NN] = acc[2];
        op[(size_t)3*NN] = acc[3];
    }
}

// ---------- fallback (r17 kernel, 165us, self-contained staging) ----------
#define IPAD 385
__global__ __launch_bounds__(512, 4)
void dtn_mfma16w(const float* __restrict__ A, const float* __restrict__ Bf,
                 const float* __restrict__ C, const int* __restrict__ x,
                 float* __restrict__ out)
{
    __shared__ __align__(16) _Float16 A2c[8 * IPAD * 8];
    __shared__ __align__(16) _Float16 Gh[8 * 16 * GSTR];
    const int t = threadIdx.x;
    const long b0 = (long)blockIdx.x * 128;
    #pragma unroll
    for (int it = 0; it < 6; ++it) {
        const int idx = t + it * 512;
        const int i = idx >> 3;
        const int a = idx & 7;
        const float4* src = reinterpret_cast<const float4*>(A + (size_t)a * NR + (size_t)i * RR);
        const float4 f0 = src[0];
        const float4 f1 = src[1];
        half8v h;
        h[0] = (_Float16)f0.x; h[1] = (_Float16)f0.y; h[2] = (_Float16)f0.z; h[3] = (_Float16)f0.w;
        h[4] = (_Float16)f1.x; h[5] = (_Float16)f1.y; h[6] = (_Float16)f1.z; h[7] = (_Float16)f1.w;
        *reinterpret_cast<half8v*>(&A2c[(size_t)(a * IPAD + i) * 8]) = h;
    }
    __syncthreads();
    const int lane = t & 63;
    const int w = t >> 6;
    _Float16* Ghw = &Gh[w * 16 * GSTR];
    {
        const int bl = lane >> 2;
        const int a0 = (lane & 3) * 2;
        const long pair = b0 + w * 16 + bl;
        const int j = x[2 * pair];
        const int k = x[2 * pair + 1];
        const float* Bj = Bf + (size_t)j * RR;
        const float* Ck = C + (size_t)k * RR + a0;
        float2 ck[8];
        #pragma unroll
        for (int c = 0; c < 8; ++c)
            ck[c] = *reinterpret_cast<const float2*>(Ck + (size_t)c * NR);
        half8v h0, h1;
        #pragma unroll
        for (int b2 = 0; b2 < 8; ++b2) {
            const float4* br = reinterpret_cast<const float4*>(Bj + (size_t)b2 * NR);
            const float4 r0 = br[0];
            const float4 r1 = br[1];
            const float s0 = r0.x * ck[0].x + r0.y * ck[1].x + r0.z * ck[2].x + r0.w * ck[3].x
                           + r1.x * ck[4].x + r1.y * ck[5].x + r1.z * ck[6].x + r1.w * ck[7].x;
            const float s1 = r0.x * ck[0].y + r0.y * ck[1].y + r0.z * ck[2].y + r0.w * ck[3].y
                           + r1.x * ck[4].y + r1.y * ck[5].y + r1.z * ck[6].y + r1.w * ck[7].y;
            h0[b2] = (_Float16)s0;
            h1[b2] = (_Float16)s1;
        }
        *reinterpret_cast<half8v*>(&Ghw[bl * GSTR + a0 * 8]) = h0;
        *reinterpret_cast<half8v*>(&Ghw[bl * GSTR + a0 * 8 + 8]) = h1;
    }
    const int a16 = lane & 15;
    const int q = lane >> 4;
    const half4v af0 = *reinterpret_cast<const half4v*>(&Ghw[a16 * GSTR +  0 + 4 * q]);
    const half4v af1 = *reinterpret_cast<const half4v*>(&Ghw[a16 * GSTR + 16 + 4 * q]);
    const half4v af2 = *reinterpret_cast<const half4v*>(&Ghw[a16 * GSTR + 32 + 4 * q]);
    const half4v af3 = *reinterpret_cast<const half4v*>(&Ghw[a16 * GSTR + 48 + 4 * q]);
    const long prow0 = b0 + w * 16 + 4 * q;
    #pragma unroll 2
    for (int nt = 0; nt < 24; ++nt) {
        const int col = nt * 16 + a16;
        f32x4 acc = {0.f, 0.f, 0.f, 0.f};
        const half4v bf0 = *reinterpret_cast<const half4v*>(
            &A2c[(size_t)((0 + (q >> 1)) * IPAD + col) * 8 + 4 * (q & 1)]);
        acc = __builtin_amdgcn_mfma_f32_16x16x16f16(af0, bf0, acc, 0, 0, 0);
        const half4v bf1 = *reinterpret_cast<const half4v*>(
            &A2c[(size_t)((2 + (q >> 1)) * IPAD + col) * 8 + 4 * (q & 1)]);
        acc = __builtin_amdgcn_mfma_f32_16x16x16f16(af1, bf1, acc, 0, 0, 0);
        const half4v bf2 = *reinterpret_cast<const half4v*>(
            &A2c[(size_t)((4 + (q >> 1)) * IPAD + col) * 8 + 4 * (q & 1)]);
        acc = __builtin_amdgcn_mfma_f32_16x16x16f16(af2, bf2, acc, 0, 0, 0);
        const half4v bf3 = *reinterpret_cast<const half4v*>(
            &A2c[(size_t)((6 + (q >> 1)) * IPAD + col) * 8 + 4 * (q & 1)]);
        acc = __builtin_amdgcn_mfma_f32_16x16x16f16(af3, bf3, acc, 0, 0, 0);
        float* op = out + (size_t)prow0 * NN + col;
        op[0]            = acc[0];
        op[(size_t)NN]   = acc[1];
        op[(size_t)2*NN] = acc[2];
        op[(size_t)3*NN] = acc[3];
    }
}

extern "C" void kernel_launch(void* const* d_in, const int* in_sizes, int n_in,
                              void* d_out, int out_size, void* d_ws, size_t ws_size,
                              hipStream_t stream) {
    const float* A  = (const float*)d_in[0];
    const float* Bf = (const float*)d_in[1];
    const float* C  = (const float*)d_in[2];
    const int*   x  = (const int*)d_in[3];
    float* out = (float*)d_out;
    const int B = in_sizes[3] / 2;           // 524288
    if (ws_size >= (size_t)NN * RR * 8 * sizeof(_Float16)) {
        _Float16* A2h = (_Float16*)d_ws;
        prep_a2<<<12, 256, 0, stream>>>(A, A2h);
        dtn_mfma16g<<<B / 128, 512, 0, stream>>>(A2h, Bf, C, x, out);
    } else {
        dtn_mfma16w<<<B / 128, 512, 0, stream>>>(A, Bf, C, x, out);
    }
}

// Round 20
// 164.550 us; speedup vs baseline: 1.0613x; 1.0259x over previous
//
#include <hip/hip_runtime.h>

#define NN 384
#define RR 8
#define NR (NN * RR)   // 3072
#define IPAD 385       // padded i-stride for A2c (breaks c-dimension bank aliasing)
#define GSTR 72        // Gh row stride in f16 (144B rows -> bank spread)

typedef _Float16 half4v __attribute__((ext_vector_type(4)));
typedef _Float16 half8v __attribute__((ext_vector_type(8)));
typedef float f32x4 __attribute__((ext_vector_type(4)));

// out[b,i] = sum_{a,b2,c} A[a,i,b2]*Bf[b2,j_b,c]*C[c,k_b,a]
// G[b2,a] = sum_c Bf[b2,j,c]*C[c,k,a];  out[b,i] = sum_p A2[i,p]*G[p], p=a*8+b2.
// CHAMPION (r17, 165us): wave-autonomous. Each wave owns 16 pairs end-to-end:
// computes G (r4-proven per-lane map) into wave-PRIVATE LDS, reads its own
// fragments (classic 16x16x16_f16 maps, r13-proven), MFMAs, stores.
// One block-wide barrier total (after A2 staging).
__global__ __launch_bounds__(512, 4)
void dtn_mfma16w(const float* __restrict__ A, const float* __restrict__ Bf,
                 const float* __restrict__ C, const int* __restrict__ x,
                 float* __restrict__ out)
{
    __shared__ __align__(16) _Float16 A2c[8 * IPAD * 8];   // 49280 B
    __shared__ __align__(16) _Float16 Gh[8 * 16 * GSTR];   // 18432 B (wave-private 2304B each)

    const int t = threadIdx.x;
    const long b0 = (long)blockIdx.x * 128;   // 128 pairs per block (8 waves x 16)

    // ---- Stage A2c[(a*IPAD+i)*8+e] = f16(A[a*NR + i*8 + e]); 3072 chunks, 6 iters.
    #pragma unroll
    for (int it = 0; it < 6; ++it) {
        const int idx = t + it * 512;     // 0..3071
        const int i = idx >> 3;
        const int a = idx & 7;
        const float4* src = reinterpret_cast<const float4*>(A + (size_t)a * NR + (size_t)i * RR);
        const float4 f0 = src[0];
        const float4 f1 = src[1];
        half8v h;
        h[0] = (_Float16)f0.x; h[1] = (_Float16)f0.y; h[2] = (_Float16)f0.z; h[3] = (_Float16)f0.w;
        h[4] = (_Float16)f1.x; h[5] = (_Float16)f1.y; h[6] = (_Float16)f1.z; h[7] = (_Float16)f1.w;
        *reinterpret_cast<half8v*>(&A2c[(size_t)(a * IPAD + i) * 8]) = h;
    }
    __syncthreads();   // the ONLY block-wide barrier

    const int lane = t & 63;
    const int w    = t >> 6;                       // wave 0..7 owns pairs b0+w*16..+15
    _Float16* Ghw  = &Gh[w * 16 * GSTR];           // wave-private G region

    // ---- G phase (r4-proven per-lane map): lane -> pair bl = lane>>2, a0 = (lane&3)*2.
    {
        const int bl = lane >> 2;
        const int a0 = (lane & 3) * 2;
        const long pair = b0 + w * 16 + bl;
        const int j = x[2 * pair];
        const int k = x[2 * pair + 1];
        const float* Bj = Bf + (size_t)j * RR;       // Bf[b2,j,c] at Bj[b2*NR + c]
        const float* Ck = C + (size_t)k * RR + a0;   // C[c,k,a0+d] at Ck[c*NR + d]
        float2 ck[8];
        #pragma unroll
        for (int c = 0; c < 8; ++c)
            ck[c] = *reinterpret_cast<const float2*>(Ck + (size_t)c * NR);
        half8v h0, h1;
        #pragma unroll
        for (int b2 = 0; b2 < 8; ++b2) {
            const float4* br = reinterpret_cast<const float4*>(Bj + (size_t)b2 * NR);
            const float4 r0 = br[0];
            const float4 r1 = br[1];
            const float s0 = r0.x * ck[0].x + r0.y * ck[1].x + r0.z * ck[2].x + r0.w * ck[3].x
                           + r1.x * ck[4].x + r1.y * ck[5].x + r1.z * ck[6].x + r1.w * ck[7].x;
            const float s1 = r0.x * ck[0].y + r0.y * ck[1].y + r0.z * ck[2].y + r0.w * ck[3].y
                           + r1.x * ck[4].y + r1.y * ck[5].y + r1.z * ck[6].y + r1.w * ck[7].y;
            h0[b2] = (_Float16)s0;
            h1[b2] = (_Float16)s1;
        }
        *reinterpret_cast<half8v*>(&Ghw[bl * GSTR + a0 * 8]) = h0;       // p = a0*8 + b2
        *reinterpret_cast<half8v*>(&Ghw[bl * GSTR + a0 * 8 + 8]) = h1;   // p = (a0+1)*8 + b2
    }
    // Wave-private RAW on LDS: compiler emits lgkmcnt wait; no barrier needed.

    const int a16 = lane & 15;
    const int q   = lane >> 4;   // 0..3

    // ---- A-fragments (r13 map): G-row = a16 (pair), k-windows 0/16/32/48 (+4q).
    const half4v af0 = *reinterpret_cast<const half4v*>(&Ghw[a16 * GSTR +  0 + 4 * q]);
    const half4v af1 = *reinterpret_cast<const half4v*>(&Ghw[a16 * GSTR + 16 + 4 * q]);
    const half4v af2 = *reinterpret_cast<const half4v*>(&Ghw[a16 * GSTR + 32 + 4 * q]);
    const half4v af3 = *reinterpret_cast<const half4v*>(&Ghw[a16 * GSTR + 48 + 4 * q]);

    const long prow0 = b0 + w * 16 + 4 * q;    // D row base (pair) for this lane

    // ---- 24 N-tiles of 16 i; B-frag (r13 map): A2[col=n0+a16][k=16kt+4q+e],
    //      p = 16kt+4q+e -> chunk c = 2kt+(q>>1), elem = 4*(q&1)+e.
    #pragma unroll 2
    for (int nt = 0; nt < 24; ++nt) {
        const int col = nt * 16 + a16;
        f32x4 acc = {0.f, 0.f, 0.f, 0.f};
        const half4v bf0 = *reinterpret_cast<const half4v*>(
            &A2c[(size_t)((0 + (q >> 1)) * IPAD + col) * 8 + 4 * (q & 1)]);
        acc = __builtin_amdgcn_mfma_f32_16x16x16f16(af0, bf0, acc, 0, 0, 0);
        const half4v bf1 = *reinterpret_cast<const half4v*>(
            &A2c[(size_t)((2 + (q >> 1)) * IPAD + col) * 8 + 4 * (q & 1)]);
        acc = __builtin_amdgcn_mfma_f32_16x16x16f16(af1, bf1, acc, 0, 0, 0);
        const half4v bf2 = *reinterpret_cast<const half4v*>(
            &A2c[(size_t)((4 + (q >> 1)) * IPAD + col) * 8 + 4 * (q & 1)]);
        acc = __builtin_amdgcn_mfma_f32_16x16x16f16(af2, bf2, acc, 0, 0, 0);
        const half4v bf3 = *reinterpret_cast<const half4v*>(
            &A2c[(size_t)((6 + (q >> 1)) * IPAD + col) * 8 + 4 * (q & 1)]);
        acc = __builtin_amdgcn_mfma_f32_16x16x16f16(af3, bf3, acc, 0, 0, 0);

        float* op = out + (size_t)prow0 * NN + col;
        op[0]            = acc[0];
        op[(size_t)NN]   = acc[1];
        op[(size_t)2*NN] = acc[2];
        op[(size_t)3*NN] = acc[3];
    }
}

extern "C" void kernel_launch(void* const* d_in, const int* in_sizes, int n_in,
                              void* d_out, int out_size, void* d_ws, size_t ws_size,
                              hipStream_t stream) {
    const float* A  = (const float*)d_in[0];
    const float* Bf = (const float*)d_in[1];
    const float* C  = (const float*)d_in[2];
    const int*   x  = (const int*)d_in[3];
    float* out = (float*)d_out;
    const int B = in_sizes[3] / 2;           // 524288
    dtn_mfma16w<<<B / 128, 512, 0, stream>>>(A, Bf, C, x, out);
}